// Round 15
// baseline (152.500 us; speedup 1.0000x reference)
//
#include <hip/hip_runtime.h>

#define NPTS 32768
#define DIM 256
#define KCODES 1024
#define NSPLIT 8                 // code-splits in the MFMA screen (128 codes/block)
#define BN 256                   // points per screen block
#define BKC 128                  // codes per screen block
#define BK 64                    // K-step (bf16) per staging iter
#define MARGIN 0.08f             // bf16 band: flag + candidate threshold
#define CVT_BLOCKS 2048          // convert grid (plus 4 enorm blocks)

typedef __attribute__((ext_vector_type(8))) short short8v;
typedef __attribute__((ext_vector_type(8))) unsigned short ushort8v;
typedef __attribute__((ext_vector_type(4))) float f32x4;

static __device__ __forceinline__ unsigned short f2bf(float f) {
    unsigned int u = __float_as_uint(f);
    unsigned int r = (u + 0x7fffu + ((u >> 16) & 1u)) >> 16;   // RNE
    return (unsigned short)r;
}

static __device__ __forceinline__ void gload16(const void* g, void* l) {
    __builtin_amdgcn_global_load_lds((const __attribute__((address_space(1))) void*)g,
                                     (__attribute__((address_space(3))) void*)l, 16, 0, 0);
}

// ------- phase 0: f32->bf16 convert (+ per-block sum x^2) and np ||e||^2 (R13 verbatim) -------
__global__ void convert_kernel(const float* __restrict__ X, const float* __restrict__ E,
                               unsigned short* __restrict__ Xb, unsigned short* __restrict__ Eb,
                               float* __restrict__ Cnp, float* __restrict__ xsq_part,
                               int* __restrict__ counters) {
#pragma clang fp contract(off)
    const int tid = threadIdx.x;
    if (blockIdx.x == 0 && tid == 0) { counters[0] = 0; counters[32] = 0; }
    if (blockIdx.x >= CVT_BLOCKS) {
        // numpy-faithful ||e||^2 (pairwise: 8 accumulators per 128-half)
        int k = (blockIdx.x - CVT_BLOCKS) * 256 + tid;
        const float* e = E + (size_t)k * DIM;
        float half[2];
        for (int h = 0; h < 2; ++h) {
            const float* b = e + h * 128;
            float s[8];
#pragma unroll
            for (int j = 0; j < 8; ++j) { float v = b[j]; s[j] = v * v; }
            for (int i = 8; i < 128; i += 8) {
#pragma unroll
                for (int j = 0; j < 8; ++j) { float v = b[i + j]; s[j] += v * v; }
            }
            half[h] = ((s[0] + s[1]) + (s[2] + s[3])) + ((s[4] + s[5]) + (s[6] + s[7]));
        }
        Cnp[k] = half[0] + half[1];
        return;
    }
    const int total = (NPTS + KCODES) * DIM / 8;
    float xsq = 0.f;
    for (int i = blockIdx.x * 256 + tid; i < total; i += CVT_BLOCKS * 256) {
        size_t e8 = (size_t)i * 8;
        const float* src; unsigned short* dst; size_t off;
        bool isX = e8 < (size_t)NPTS * DIM;
        if (isX) { src = X; dst = Xb; off = e8; }
        else { src = E; dst = Eb; off = e8 - (size_t)NPTS * DIM; }
        float4 f0 = *(const float4*)(src + off);
        float4 f1 = *(const float4*)(src + off + 4);
        ushort8v v;
        v[0] = f2bf(f0.x); v[1] = f2bf(f0.y); v[2] = f2bf(f0.z); v[3] = f2bf(f0.w);
        v[4] = f2bf(f1.x); v[5] = f2bf(f1.y); v[6] = f2bf(f1.z); v[7] = f2bf(f1.w);
        *(ushort8v*)(dst + off) = v;
        if (isX)
            xsq += f0.x * f0.x + f0.y * f0.y + f0.z * f0.z + f0.w * f0.w
                 + f1.x * f1.x + f1.y * f1.y + f1.z * f1.z + f1.w * f1.w;
    }
    __shared__ float red[256];
    red[tid] = xsq;
    __syncthreads();
#pragma unroll
    for (int s = 128; s > 0; s >>= 1) {
        if (tid < s) red[tid] += red[tid + s];
        __syncthreads();
    }
    if (tid == 0) xsq_part[blockIdx.x] = red[0];
}

// ------- phase 1: bf16-MFMA screen (R12/R13 champion, byte-verbatim) -------
__global__ __launch_bounds__(256, 2) void dist_kernel(
        const unsigned short* __restrict__ Xb, const unsigned short* __restrict__ Eb,
        const float* __restrict__ Cnp,
        float* __restrict__ ws_m1, unsigned int* __restrict__ cand) {
    __shared__ unsigned short xs[BN * BK];    // 32 KB
    __shared__ unsigned short es[BKC * BK];   // 16 KB

    const int tid = threadIdx.x;
    const int lane = tid & 63;
    const int wave = tid >> 6;
    const int lg = lane >> 4, lc = lane & 15;
    const int pbase = blockIdx.x * BN;
    const int split = blockIdx.y;
    const int cbase = split * BKC;

    f32x4 acc[4][8];
#pragma unroll
    for (int i = 0; i < 4; ++i)
#pragma unroll
        for (int j = 0; j < 8; ++j) acc[i][j] = (f32x4){0.f, 0.f, 0.f, 0.f};

    for (int ks = 0; ks < DIM / BK; ++ks) {
        const int k0 = ks * BK;
        __syncthreads();
#pragma unroll
        for (int q = 0; q < 8; ++q) {
            const int B = wave * 8192 + q * 1024 + lane * 16;
            const int row = B >> 7;
            const int cs = ((B >> 4) & 7) ^ (row & 7);
            gload16(Xb + (size_t)(pbase + row) * DIM + k0 + cs * 8,
                    (char*)xs + wave * 8192 + q * 1024);
        }
#pragma unroll
        for (int q = 0; q < 4; ++q) {
            const int B = wave * 4096 + q * 1024 + lane * 16;
            const int row = B >> 7;
            const int cs = ((B >> 4) & 7) ^ (row & 7);
            gload16(Eb + (size_t)(cbase + row) * DIM + k0 + cs * 8,
                    (char*)es + wave * 4096 + q * 1024);
        }
        __syncthreads();
#pragma unroll
        for (int kk = 0; kk < 2; ++kk) {
            short8v a[4];
#pragma unroll
            for (int f = 0; f < 4; ++f) {
                int row = wave * 64 + f * 16 + lc;
                int cs = (kk * 4 + lg) ^ (row & 7);
                a[f] = *(const short8v*)&xs[row * BK + cs * 8];
            }
#pragma unroll
            for (int j = 0; j < 8; ++j) {
                int row = j * 16 + lc;
                int cs = (kk * 4 + lg) ^ (row & 7);
                short8v b = *(const short8v*)&es[row * BK + cs * 8];
#pragma unroll
                for (int i = 0; i < 4; ++i)
                    acc[i][j] = __builtin_amdgcn_mfma_f32_16x16x32_bf16(a[i], b, acc[i][j], 0, 0, 0);
            }
        }
    }

    float en8[8];
#pragma unroll
    for (int j = 0; j < 8; ++j) en8[j] = Cnp[cbase + j * 16 + lc];

    float m1[4][4];
#pragma unroll
    for (int i = 0; i < 4; ++i)
#pragma unroll
        for (int r = 0; r < 4; ++r) m1[i][r] = 3.4e38f;
#pragma unroll
    for (int j = 0; j < 8; ++j)
#pragma unroll
        for (int i = 0; i < 4; ++i)
#pragma unroll
            for (int r = 0; r < 4; ++r)
                m1[i][r] = fminf(m1[i][r], __builtin_fmaf(-2.f, acc[i][j][r], en8[j]));
#pragma unroll
    for (int m = 1; m < 16; m <<= 1)
#pragma unroll
        for (int i = 0; i < 4; ++i)
#pragma unroll
            for (int r = 0; r < 4; ++r)
                m1[i][r] = fminf(m1[i][r], __shfl_xor(m1[i][r], m));

#pragma unroll
    for (int i = 0; i < 4; ++i)
#pragma unroll
        for (int r = 0; r < 4; ++r) {
            float thr = m1[i][r] + MARGIN;
            unsigned int sl[8];
#pragma unroll
            for (int j = 0; j < 8; ++j) {
                float d = __builtin_fmaf(-2.f, acc[i][j][r], en8[j]);
                unsigned long long mm = __ballot(d <= thr);
                sl[j] = (unsigned int)((mm >> (lg * 16)) & 0xFFFFull);
            }
            if (lc == 0) {
                int p = pbase + wave * 64 + i * 16 + lg * 4 + r;
                uint4 w4 = { sl[0] | (sl[1] << 16), sl[2] | (sl[3] << 16),
                             sl[4] | (sl[5] << 16), sl[6] | (sl[7] << 16) };
                *(uint4*)&cand[((size_t)p * NSPLIT + split) * 4] = w4;
                ws_m1[(size_t)p * NSPLIT + split] = m1[i][r];
            }
        }
}

// ------- phase 2: resolve + fused np-rescore (NO d_out writes -> race-free) -------
// Phase A: combine splits, derive index, flag, v1 partials + last-block loss.
// Phase B: R13's rescore loop verbatim over the block-local flag list
// (lockstep batches of 4 waves, barriers block-uniform since lcnt is shared);
// per-candidate arithmetic bit-identical to rounds 3-13.
__global__ __launch_bounds__(256) void resolve_kernel(
        const float* __restrict__ ws_m1, const unsigned int* __restrict__ cand,
        const float* __restrict__ X, const float* __restrict__ E,
        const float* __restrict__ Cnp, int* __restrict__ counters,
        const float* __restrict__ xsq_part, float* __restrict__ v1_part,
        float* __restrict__ out_loss, int* __restrict__ final_idx) {
#pragma clang fp contract(off)
    const int tid = threadIdx.x;
    const int lane = tid & 63;
    const int wave = tid >> 6;
    const int pblk = blockIdx.x * 256;
    const int p = pblk + tid;

    __shared__ float xsh[4][DIM];
    __shared__ int fidx[256];
    __shared__ int llist[256];
    __shared__ int lcnt;
    __shared__ float red[256];
    __shared__ double dred[256];
    __shared__ int amlast;

    if (tid == 0) lcnt = 0;
    __syncthreads();

    // ---- phase A (R13 resolve logic) ----
    float4 ma = *(const float4*)&ws_m1[(size_t)p * NSPLIT];
    float4 mb = *(const float4*)&ws_m1[(size_t)p * NSPLIT + 4];
    float m[8] = { ma.x, ma.y, ma.z, ma.w, mb.x, mb.y, mb.z, mb.w };
    float v1 = m[0]; int sstar = 0;
#pragma unroll
    for (int s = 1; s < NSPLIT; ++s)
        if (m[s] < v1) { v1 = m[s]; sstar = s; }
    float thr = v1 + MARGIN;                // same rounded op as dist's ballot threshold
    bool flag = false;
#pragma unroll
    for (int s = 0; s < NSPLIT; ++s)
        if (s != sstar && m[s] <= thr) flag = true;
    uint4 w4 = *(const uint4*)&cand[((size_t)p * NSPLIT + sstar) * 4];
    int pc = __builtin_popcount(w4.x) + __builtin_popcount(w4.y)
           + __builtin_popcount(w4.z) + __builtin_popcount(w4.w);
    flag = flag || (pc > 1);
    int idx;
    if (w4.x)      idx = __builtin_ctz(w4.x);
    else if (w4.y) idx = 32 + __builtin_ctz(w4.y);
    else if (w4.z) idx = 64 + __builtin_ctz(w4.z);
    else           idx = 96 + __builtin_ctz(w4.w);
    fidx[tid] = sstar * BKC + idx;
    if (flag) {
        int slot = atomicAdd(&lcnt, 1);
        llist[slot] = tid;
    }

    // v1 partials (loss = 1.25*(sum v1 + sum x^2)/(N*D), error ~3e-7)
    red[tid] = v1;
    __syncthreads();
#pragma unroll
    for (int s = 128; s > 0; s >>= 1) {
        if (tid < s) red[tid] += red[tid + s];
        __syncthreads();
    }
    if (tid == 0) v1_part[blockIdx.x] = red[0];

    if (tid == 0) {
        __threadfence();
        amlast = (atomicAdd(&counters[32], 1) == (int)gridDim.x - 1);
    }
    __syncthreads();
    if (amlast) {
        __threadfence();
        double s = 0.0;
        for (int i = tid; i < CVT_BLOCKS; i += 256) s += (double)xsq_part[i];
        for (int i = tid; i < NPTS / 256; i += 256) s += (double)v1_part[i];
        dred[tid] = s;
        __syncthreads();
#pragma unroll
        for (int t = 128; t > 0; t >>= 1) {
            if (tid < t) dred[tid] += dred[tid + t];
            __syncthreads();
        }
        if (tid == 0)
            out_loss[0] = (float)(1.25 * dred[0] / (double)((size_t)NPTS * DIM));
    }

    // ---- phase B: np-emulating rescore, R13 loop structure verbatim ----
    // d = fl32(fl32(A - 2*B) + C); B = sequential ascending-d fp32 fma chain;
    // A = np-pairwise sum x^2; C = Cnp — bit-identical to rounds 3-13.
    for (int base = 0; base < lcnt; base += 4) {
        const int li = base + wave;
        const bool active = (li < lcnt);
        const int pl = llist[active ? li : (lcnt - 1)];
        const int pg = pblk + pl;
        __syncthreads();
        *(float4*)&xsh[wave][lane * 4] = *(const float4*)(X + (size_t)pg * DIM + lane * 4);
        __syncthreads();

        float s = 0.f;
        if (lane < 16) {
            const int h = lane >> 3, j = lane & 7;
            float v = xsh[wave][h * 128 + j];
            s = v * v;
            for (int i = 8; i < 128; i += 8) {
                float w = xsh[wave][h * 128 + i + j];
                s += w * w;
            }
        }
        float t0 = __shfl(s, 0), t1 = __shfl(s, 1), t2 = __shfl(s, 2), t3 = __shfl(s, 3);
        float t4 = __shfl(s, 4), t5 = __shfl(s, 5), t6 = __shfl(s, 6), t7 = __shfl(s, 7);
        float u0 = __shfl(s, 8), u1 = __shfl(s, 9), u2 = __shfl(s, 10), u3 = __shfl(s, 11);
        float u4 = __shfl(s, 12), u5 = __shfl(s, 13), u6 = __shfl(s, 14), u7 = __shfl(s, 15);
        const float A = (((t0 + t1) + (t2 + t3)) + ((t4 + t5) + (t6 + t7)))
                      + (((u0 + u1) + (u2 + u3)) + ((u4 + u5) + (u6 + u7)));

        float bv = 3.4e38f; int bi = 0x7FFFFFFF;
        if (lane < 32) {
            unsigned int bits = cand[(size_t)pg * 32 + lane];
            const int cb = (lane >> 2) * 128 + (lane & 3) * 32;
            while (bits) {
                int t = __builtin_ctz(bits);
                bits &= bits - 1;
                int c = cb + t;
                const float4* er4 = (const float4*)(E + (size_t)c * DIM);
                float acc = 0.f;
                for (int d4 = 0; d4 < DIM / 4; ++d4) {
                    float4 e4 = er4[d4];
                    float4 x4 = *(const float4*)&xsh[wave][d4 * 4];
                    acc = __builtin_fmaf(x4.x, e4.x, acc);
                    acc = __builtin_fmaf(x4.y, e4.y, acc);
                    acc = __builtin_fmaf(x4.z, e4.z, acc);
                    acc = __builtin_fmaf(x4.w, e4.w, acc);
                }
                float tt = A - 2.0f * acc;      // rounded subtract
                float dnp = tt + Cnp[c];        // rounded add (decisive grid)
                if (dnp < bv) { bv = dnp; bi = c; }
            }
        }
#pragma unroll
        for (int mm = 1; mm < 64; mm <<= 1) {
            float ov = __shfl_xor(bv, mm);
            int oi = __shfl_xor(bi, mm);
            if (ov < bv || (ov == bv && oi < bi)) { bv = ov; bi = oi; }
        }
        if (active && lane == 0) fidx[pl] = bi;
    }
    __syncthreads();

    final_idx[p] = fidx[tid];
}

// ------- phase 3: gather — write quantized rows + indices (R13 verbatim; runs
// after resolve completes, so out_q-overlapping staging is dead by then) -------
__global__ void gather_kernel(const float* __restrict__ E, const int* __restrict__ final_idx,
                              float* __restrict__ out_q, float* __restrict__ out_idx) {
    const int tid = threadIdx.x;
    const int p = blockIdx.x * 16 + (tid >> 4);
    const int c = tid & 15;
    const int bi = final_idx[p];
#pragma unroll
    for (int k = 0; k < 4; ++k) {
        int d4 = c + k * 16;
        float4 e4 = *(const float4*)(E + (size_t)bi * DIM + d4 * 4);
        *(float4*)(out_q + (size_t)p * DIM + d4 * 4) = e4;
    }
    if (c == 0) out_idx[p] = (float)bi;
}

extern "C" void kernel_launch(void* const* d_in, const int* in_sizes, int n_in,
                              void* d_out, int out_size, void* d_ws, size_t ws_size,
                              hipStream_t stream) {
    const float* X = (const float*)d_in[0];   // [32768, 256]
    const float* E = (const float*)d_in[1];   // [1024, 256]
    float* out = (float*)d_out;
    float* out_q = out;                                 // 8388608 floats
    float* out_loss = out + (size_t)NPTS * DIM;         // 1 float
    float* out_idx = out + (size_t)NPTS * DIM + 1;      // 32768 floats

    // staging inside out_q (read only by dist/resolve; gather runs after):
    // Xb (16.8MB) + Eb (0.5MB) + cand (4.2MB) = 21.5MB < 33.5MB
    unsigned short* Xb = (unsigned short*)d_out;
    unsigned short* Eb = Xb + (size_t)NPTS * DIM;
    unsigned int* cand = (unsigned int*)(Eb + (size_t)KCODES * DIM);  // [NPTS][8][4] u32

    float* ws = (float*)d_ws;
    float* Cnp = ws;                                    // 1024
    float* ws_m1 = Cnp + KCODES;                        // [NPTS][8] floats (1MB)
    int* final_idx = (int*)(ws_m1 + (size_t)NPTS * NSPLIT);  // 32768 ints
    int* counters = final_idx + NPTS;                   // 64 ints ([32]=done)
    float* xsq_part = (float*)(counters + 64);          // 2048 floats
    float* v1_part = xsq_part + CVT_BLOCKS;             // 128 floats

    convert_kernel<<<CVT_BLOCKS + KCODES / 256, 256, 0, stream>>>(X, E, Xb, Eb, Cnp,
                                                                  xsq_part, counters);
    dist_kernel<<<dim3(NPTS / BN, NSPLIT), 256, 0, stream>>>(Xb, Eb, Cnp, ws_m1, cand);
    resolve_kernel<<<NPTS / 256, 256, 0, stream>>>(ws_m1, cand, X, E, Cnp, counters,
                                                   xsq_part, v1_part, out_loss, final_idx);
    gather_kernel<<<NPTS / 16, 256, 0, stream>>>(E, final_idx, out_q, out_idx);
}

// Round 16
// 87.890 us; speedup vs baseline: 1.7351x; 1.7351x over previous
//
#include <hip/hip_runtime.h>

#define NPTS 32768
#define DIM 256
#define KCODES 1024
#define NSPLIT 8                 // code-splits in the MFMA screen (128 codes/block)
#define BN 256                   // points per screen block
#define BKC 128                  // codes per screen block
#define BK 64                    // K-step (bf16) per staging iter
#define MARGIN 0.08f             // bf16 band: flag + candidate threshold
#define CVT_BLOCKS 2048          // convert grid (plus 4 enorm blocks)
#define MAXPAIRS (2500000)       // pair-list capacity (10MB in out_q scratch)

typedef __attribute__((ext_vector_type(8))) short short8v;
typedef __attribute__((ext_vector_type(8))) unsigned short ushort8v;
typedef __attribute__((ext_vector_type(4))) float f32x4;

static __device__ __forceinline__ unsigned short f2bf(float f) {
    unsigned int u = __float_as_uint(f);
    unsigned int r = (u + 0x7fffu + ((u >> 16) & 1u)) >> 16;   // RNE
    return (unsigned short)r;
}

static __device__ __forceinline__ void gload16(const void* g, void* l) {
    __builtin_amdgcn_global_load_lds((const __attribute__((address_space(1))) void*)g,
                                     (__attribute__((address_space(3))) void*)l, 16, 0, 0);
}

// ------- phase 0: f32->bf16 convert (+ per-block sum x^2) and np ||e||^2 (R13 verbatim) -------
__global__ void convert_kernel(const float* __restrict__ X, const float* __restrict__ E,
                               unsigned short* __restrict__ Xb, unsigned short* __restrict__ Eb,
                               float* __restrict__ Cnp, float* __restrict__ xsq_part,
                               int* __restrict__ counters) {
#pragma clang fp contract(off)
    const int tid = threadIdx.x;
    if (blockIdx.x == 0 && tid == 0) { counters[0] = 0; counters[32] = 0; }
    if (blockIdx.x >= CVT_BLOCKS) {
        // numpy-faithful ||e||^2 (pairwise: 8 accumulators per 128-half)
        int k = (blockIdx.x - CVT_BLOCKS) * 256 + tid;
        const float* e = E + (size_t)k * DIM;
        float half[2];
        for (int h = 0; h < 2; ++h) {
            const float* b = e + h * 128;
            float s[8];
#pragma unroll
            for (int j = 0; j < 8; ++j) { float v = b[j]; s[j] = v * v; }
            for (int i = 8; i < 128; i += 8) {
#pragma unroll
                for (int j = 0; j < 8; ++j) { float v = b[i + j]; s[j] += v * v; }
            }
            half[h] = ((s[0] + s[1]) + (s[2] + s[3])) + ((s[4] + s[5]) + (s[6] + s[7]));
        }
        Cnp[k] = half[0] + half[1];
        return;
    }
    const int total = (NPTS + KCODES) * DIM / 8;
    float xsq = 0.f;
    for (int i = blockIdx.x * 256 + tid; i < total; i += CVT_BLOCKS * 256) {
        size_t e8 = (size_t)i * 8;
        const float* src; unsigned short* dst; size_t off;
        bool isX = e8 < (size_t)NPTS * DIM;
        if (isX) { src = X; dst = Xb; off = e8; }
        else { src = E; dst = Eb; off = e8 - (size_t)NPTS * DIM; }
        float4 f0 = *(const float4*)(src + off);
        float4 f1 = *(const float4*)(src + off + 4);
        ushort8v v;
        v[0] = f2bf(f0.x); v[1] = f2bf(f0.y); v[2] = f2bf(f0.z); v[3] = f2bf(f0.w);
        v[4] = f2bf(f1.x); v[5] = f2bf(f1.y); v[6] = f2bf(f1.z); v[7] = f2bf(f1.w);
        *(ushort8v*)(dst + off) = v;
        if (isX)
            xsq += f0.x * f0.x + f0.y * f0.y + f0.z * f0.z + f0.w * f0.w
                 + f1.x * f1.x + f1.y * f1.y + f1.z * f1.z + f1.w * f1.w;
    }
    __shared__ float red[256];
    red[tid] = xsq;
    __syncthreads();
#pragma unroll
    for (int s = 128; s > 0; s >>= 1) {
        if (tid < s) red[tid] += red[tid + s];
        __syncthreads();
    }
    if (tid == 0) xsq_part[blockIdx.x] = red[0];
}

// ------- phase 1: bf16-MFMA screen (R12/R13 champion, byte-verbatim) -------
__global__ __launch_bounds__(256, 2) void dist_kernel(
        const unsigned short* __restrict__ Xb, const unsigned short* __restrict__ Eb,
        const float* __restrict__ Cnp,
        float* __restrict__ ws_m1, unsigned int* __restrict__ cand) {
    __shared__ unsigned short xs[BN * BK];    // 32 KB
    __shared__ unsigned short es[BKC * BK];   // 16 KB

    const int tid = threadIdx.x;
    const int lane = tid & 63;
    const int wave = tid >> 6;
    const int lg = lane >> 4, lc = lane & 15;
    const int pbase = blockIdx.x * BN;
    const int split = blockIdx.y;
    const int cbase = split * BKC;

    f32x4 acc[4][8];
#pragma unroll
    for (int i = 0; i < 4; ++i)
#pragma unroll
        for (int j = 0; j < 8; ++j) acc[i][j] = (f32x4){0.f, 0.f, 0.f, 0.f};

    for (int ks = 0; ks < DIM / BK; ++ks) {
        const int k0 = ks * BK;
        __syncthreads();
#pragma unroll
        for (int q = 0; q < 8; ++q) {
            const int B = wave * 8192 + q * 1024 + lane * 16;
            const int row = B >> 7;
            const int cs = ((B >> 4) & 7) ^ (row & 7);
            gload16(Xb + (size_t)(pbase + row) * DIM + k0 + cs * 8,
                    (char*)xs + wave * 8192 + q * 1024);
        }
#pragma unroll
        for (int q = 0; q < 4; ++q) {
            const int B = wave * 4096 + q * 1024 + lane * 16;
            const int row = B >> 7;
            const int cs = ((B >> 4) & 7) ^ (row & 7);
            gload16(Eb + (size_t)(cbase + row) * DIM + k0 + cs * 8,
                    (char*)es + wave * 4096 + q * 1024);
        }
        __syncthreads();
#pragma unroll
        for (int kk = 0; kk < 2; ++kk) {
            short8v a[4];
#pragma unroll
            for (int f = 0; f < 4; ++f) {
                int row = wave * 64 + f * 16 + lc;
                int cs = (kk * 4 + lg) ^ (row & 7);
                a[f] = *(const short8v*)&xs[row * BK + cs * 8];
            }
#pragma unroll
            for (int j = 0; j < 8; ++j) {
                int row = j * 16 + lc;
                int cs = (kk * 4 + lg) ^ (row & 7);
                short8v b = *(const short8v*)&es[row * BK + cs * 8];
#pragma unroll
                for (int i = 0; i < 4; ++i)
                    acc[i][j] = __builtin_amdgcn_mfma_f32_16x16x32_bf16(a[i], b, acc[i][j], 0, 0, 0);
            }
        }
    }

    float en8[8];
#pragma unroll
    for (int j = 0; j < 8; ++j) en8[j] = Cnp[cbase + j * 16 + lc];

    float m1[4][4];
#pragma unroll
    for (int i = 0; i < 4; ++i)
#pragma unroll
        for (int r = 0; r < 4; ++r) m1[i][r] = 3.4e38f;
#pragma unroll
    for (int j = 0; j < 8; ++j)
#pragma unroll
        for (int i = 0; i < 4; ++i)
#pragma unroll
            for (int r = 0; r < 4; ++r)
                m1[i][r] = fminf(m1[i][r], __builtin_fmaf(-2.f, acc[i][j][r], en8[j]));
#pragma unroll
    for (int m = 1; m < 16; m <<= 1)
#pragma unroll
        for (int i = 0; i < 4; ++i)
#pragma unroll
            for (int r = 0; r < 4; ++r)
                m1[i][r] = fminf(m1[i][r], __shfl_xor(m1[i][r], m));

#pragma unroll
    for (int i = 0; i < 4; ++i)
#pragma unroll
        for (int r = 0; r < 4; ++r) {
            float thr = m1[i][r] + MARGIN;
            unsigned int sl[8];
#pragma unroll
            for (int j = 0; j < 8; ++j) {
                float d = __builtin_fmaf(-2.f, acc[i][j][r], en8[j]);
                unsigned long long mm = __ballot(d <= thr);
                sl[j] = (unsigned int)((mm >> (lg * 16)) & 0xFFFFull);
            }
            if (lc == 0) {
                int p = pbase + wave * 64 + i * 16 + lg * 4 + r;
                uint4 w4 = { sl[0] | (sl[1] << 16), sl[2] | (sl[3] << 16),
                             sl[4] | (sl[5] << 16), sl[6] | (sl[7] << 16) };
                *(uint4*)&cand[((size_t)p * NSPLIT + split) * 4] = w4;
                ws_m1[(size_t)p * NSPLIT + split] = m1[i][r];
            }
        }
}

// ------- phase 2: resolve — combine, flag, emit (point,code) pairs, loss -------
// keymin[p] = ~0 for flagged (to be atomicMin'd by rescore), screen idx else.
__global__ void resolve_kernel(const float* __restrict__ ws_m1, const unsigned int* __restrict__ cand,
                               unsigned long long* __restrict__ keymin,
                               unsigned int* __restrict__ pairs, int* __restrict__ counters,
                               const float* __restrict__ xsq_part, float* __restrict__ v1_part,
                               float* __restrict__ out_loss) {
    const int tid = threadIdx.x;
    const int p = blockIdx.x * 256 + tid;
    float4 ma = *(const float4*)&ws_m1[(size_t)p * NSPLIT];
    float4 mb = *(const float4*)&ws_m1[(size_t)p * NSPLIT + 4];
    float m[8] = { ma.x, ma.y, ma.z, ma.w, mb.x, mb.y, mb.z, mb.w };
    float v1 = m[0]; int sstar = 0;
#pragma unroll
    for (int s = 1; s < NSPLIT; ++s)
        if (m[s] < v1) { v1 = m[s]; sstar = s; }
    float thr = v1 + MARGIN;                // same rounded op as dist's ballot threshold
    bool flag = false;
#pragma unroll
    for (int s = 0; s < NSPLIT; ++s)
        if (s != sstar && m[s] <= thr) flag = true;
    uint4 w4 = *(const uint4*)&cand[((size_t)p * NSPLIT + sstar) * 4];
    int pc = __builtin_popcount(w4.x) + __builtin_popcount(w4.y)
           + __builtin_popcount(w4.z) + __builtin_popcount(w4.w);
    flag = flag || (pc > 1);
    int idx;
    if (w4.x)      idx = __builtin_ctz(w4.x);
    else if (w4.y) idx = 32 + __builtin_ctz(w4.y);
    else if (w4.z) idx = 64 + __builtin_ctz(w4.z);
    else           idx = 96 + __builtin_ctz(w4.w);

    if (!flag) {
        keymin[p] = (unsigned long long)(sstar * BKC + idx);
    } else {
        keymin[p] = ~0ULL;
        // emit all candidate (p, c) pairs across the 8 split bitmaps
        uint4 wb[8]; int tot = 0;
#pragma unroll
        for (int s = 0; s < NSPLIT; ++s) {
            wb[s] = *(const uint4*)&cand[((size_t)p * NSPLIT + s) * 4];
            tot += __builtin_popcount(wb[s].x) + __builtin_popcount(wb[s].y)
                 + __builtin_popcount(wb[s].z) + __builtin_popcount(wb[s].w);
        }
        int slot = atomicAdd(&counters[0], tot);
#pragma unroll
        for (int s = 0; s < NSPLIT; ++s) {
            unsigned int ww[4] = { wb[s].x, wb[s].y, wb[s].z, wb[s].w };
#pragma unroll
            for (int w = 0; w < 4; ++w) {
                unsigned int bits = ww[w];
                while (bits) {
                    int t = __builtin_ctz(bits);
                    bits &= bits - 1;
                    int c = s * BKC + w * 32 + t;
                    if (slot < MAXPAIRS) pairs[slot] = ((unsigned)p << 10) | (unsigned)c;
                    ++slot;
                }
            }
        }
    }

    // v1 partials (loss = 1.25*(sum v1 + sum x^2)/(N*D), error ~3e-7)
    __shared__ float red[256];
    red[tid] = v1;
    __syncthreads();
#pragma unroll
    for (int s = 128; s > 0; s >>= 1) {
        if (tid < s) red[tid] += red[tid + s];
        __syncthreads();
    }
    if (tid == 0) v1_part[blockIdx.x] = red[0];

    __shared__ int amlast;
    if (tid == 0) {
        __threadfence();
        amlast = (atomicAdd(&counters[32], 1) == (int)gridDim.x - 1);
    }
    __syncthreads();
    if (amlast) {
        __threadfence();
        double s = 0.0;
        for (int i = tid; i < CVT_BLOCKS; i += 256) s += (double)xsq_part[i];
        for (int i = tid; i < NPTS / 256; i += 256) s += (double)v1_part[i];
        __shared__ double dred[256];
        dred[tid] = s;
        __syncthreads();
#pragma unroll
        for (int t = 128; t > 0; t >>= 1) {
            if (tid < t) dred[tid] += dred[tid + t];
            __syncthreads();
        }
        if (tid == 0)
            out_loss[0] = (float)(1.25 * dred[0] / (double)((size_t)NPTS * DIM));
    }
}

// ------- phase 3: pair-parallel np-emulating rescore -------
// One thread per (point, code) pair. d = fl32(fl32(A - 2*B) + C);
// A = per-thread np-pairwise sum x^2 (identical order to the prior wave
// version: half0-tree + half1-tree); B = sequential ascending-d fp32 fma
// chain; C = Cnp. argmin via atomicMin on (sortable(d)<<32 | c): monotone
// float map; lowest-index tie-break = numpy first-occurrence.
__global__ __launch_bounds__(256) void rescore_pairs_kernel(
        const float* __restrict__ X, const float* __restrict__ E,
        const float* __restrict__ Cnp, const unsigned int* __restrict__ pairs,
        const int* __restrict__ counters, unsigned long long* __restrict__ keymin) {
#pragma clang fp contract(off)
    const int np = min(counters[0], MAXPAIRS);
    for (int i = blockIdx.x * 256 + threadIdx.x; i < np; i += gridDim.x * 256) {
        const unsigned int pr = pairs[i];
        const int p = pr >> 10;
        const int c = pr & 1023;
        const float* x = X + (size_t)p * DIM;

        // A: np-pairwise sum of x^2 (8 accumulators per 128-half)
        float half[2];
        for (int h = 0; h < 2; ++h) {
            const float* b = x + h * 128;
            float s[8];
#pragma unroll
            for (int j = 0; j < 8; ++j) { float v = b[j]; s[j] = v * v; }
            for (int i8 = 8; i8 < 128; i8 += 8) {
#pragma unroll
                for (int j = 0; j < 8; ++j) { float v = b[i8 + j]; s[j] += v * v; }
            }
            half[h] = ((s[0] + s[1]) + (s[2] + s[3])) + ((s[4] + s[5]) + (s[6] + s[7]));
        }
        const float A = half[0] + half[1];

        // B: sequential ascending-d fma chain
        const float4* er4 = (const float4*)(E + (size_t)c * DIM);
        const float4* xr4 = (const float4*)x;
        float acc = 0.f;
        for (int d4 = 0; d4 < DIM / 4; ++d4) {
            float4 e4 = er4[d4];
            float4 x4 = xr4[d4];
            acc = __builtin_fmaf(x4.x, e4.x, acc);
            acc = __builtin_fmaf(x4.y, e4.y, acc);
            acc = __builtin_fmaf(x4.z, e4.z, acc);
            acc = __builtin_fmaf(x4.w, e4.w, acc);
        }
        float tt = A - 2.0f * acc;          // rounded subtract
        float dnp = tt + Cnp[c];            // rounded add (decisive grid)

        unsigned int ub = __float_as_uint(dnp);
        unsigned int sk = (ub & 0x80000000u) ? ~ub : (ub | 0x80000000u);
        unsigned long long key = ((unsigned long long)sk << 32) | (unsigned)c;
        atomicMin(&keymin[p], key);
    }
}

// ------- phase 4: gather — write quantized rows + indices -------
__global__ void gather_kernel(const float* __restrict__ E,
                              const unsigned long long* __restrict__ keymin,
                              float* __restrict__ out_q, float* __restrict__ out_idx) {
    const int tid = threadIdx.x;
    const int p = blockIdx.x * 16 + (tid >> 4);
    const int c = tid & 15;
    const int bi = (int)(keymin[p] & 1023ULL);
#pragma unroll
    for (int k = 0; k < 4; ++k) {
        int d4 = c + k * 16;
        float4 e4 = *(const float4*)(E + (size_t)bi * DIM + d4 * 4);
        *(float4*)(out_q + (size_t)p * DIM + d4 * 4) = e4;
    }
    if (c == 0) out_idx[p] = (float)bi;
}

extern "C" void kernel_launch(void* const* d_in, const int* in_sizes, int n_in,
                              void* d_out, int out_size, void* d_ws, size_t ws_size,
                              hipStream_t stream) {
    const float* X = (const float*)d_in[0];   // [32768, 256]
    const float* E = (const float*)d_in[1];   // [1024, 256]
    float* out = (float*)d_out;
    float* out_q = out;                                 // 8388608 floats
    float* out_loss = out + (size_t)NPTS * DIM;         // 1 float
    float* out_idx = out + (size_t)NPTS * DIM + 1;      // 32768 floats

    // staging inside out_q (read only by dist/resolve/rescore; gather runs after):
    // Xb (16.8MB) + Eb (0.5MB) + cand (4.2MB) + pairs (10MB) = 31.5MB < 33.5MB
    unsigned short* Xb = (unsigned short*)d_out;
    unsigned short* Eb = Xb + (size_t)NPTS * DIM;
    unsigned int* cand = (unsigned int*)(Eb + (size_t)KCODES * DIM);  // [NPTS][8][4] u32
    unsigned int* pairs = cand + (size_t)NPTS * NSPLIT * 4;           // MAXPAIRS u32

    float* ws = (float*)d_ws;
    float* Cnp = ws;                                    // 1024
    float* ws_m1 = Cnp + KCODES;                        // [NPTS][8] floats (1MB)
    int* counters = (int*)(ws_m1 + (size_t)NPTS * NSPLIT);   // 64 ints ([0]=pairs, [32]=done)
    float* xsq_part = (float*)(counters + 64);          // 2048 floats
    float* v1_part = xsq_part + CVT_BLOCKS;             // 128 floats
    unsigned long long* keymin =
        (unsigned long long*)(((size_t)(v1_part + NPTS / 256) + 7) & ~(size_t)7);  // NPTS u64

    convert_kernel<<<CVT_BLOCKS + KCODES / 256, 256, 0, stream>>>(X, E, Xb, Eb, Cnp,
                                                                  xsq_part, counters);
    dist_kernel<<<dim3(NPTS / BN, NSPLIT), 256, 0, stream>>>(Xb, Eb, Cnp, ws_m1, cand);
    resolve_kernel<<<NPTS / 256, 256, 0, stream>>>(ws_m1, cand, keymin, pairs, counters,
                                                   xsq_part, v1_part, out_loss);
    rescore_pairs_kernel<<<512, 256, 0, stream>>>(X, E, Cnp, pairs, counters, keymin);
    gather_kernel<<<NPTS / 16, 256, 0, stream>>>(E, keymin, out_q, out_idx);
}